// Round 3
// baseline (206.209 us; speedup 1.0000x reference)
//
#include <hip/hip_runtime.h>
#include <hip/hip_bf16.h>
#include <math.h>

#define S_LEN 2048
#define E_DIM 1024
#define NHEAD 8
#define DHEAD 128
#define MEPS 1e-6f
#define LNEPS 1e-5f

typedef __bf16 bf16x8 __attribute__((ext_vector_type(8)));
typedef float f32x4 __attribute__((ext_vector_type(4)));

__device__ inline void split8(const float* x, bf16x8& hi, bf16x8& lo) {
#pragma unroll
  for (int e = 0; e < 8; ++e) {
    float v = x[e];
    __bf16 h = (__bf16)v;
    hi[e] = h;
    lo[e] = (__bf16)(v - (float)h);
  }
}

// ---------- kernel 0: pre-convert K,V to fragment-major bf16 hi/lo ----------
// KfH/KfL layout: [h][kvt][f=ct*4+kc][lane][8]  elem = K[kvt*64+ct*16+(l&15)][h*128+kc*32+(l>>4)*8+e]
// VfH/VfL layout: [h][kvt][f=kc2*8+nt][lane][8] elem = V[kvt*64+kc2*32+(l>>4)*8+e][h*128+nt*16+(l&15)]
__global__ __launch_bounds__(256) void convert_kernel(
    const float* __restrict__ k, const float* __restrict__ v,
    __bf16* __restrict__ KfH, __bf16* __restrict__ KfL,
    __bf16* __restrict__ VfH, __bf16* __restrict__ VfL) {
  int h = blockIdx.x >> 5, kvt = blockIdx.x & 31;
  int t = threadIdx.x;
  __shared__ float Kl[64][132], Vl[64][132];
  int kvbase = kvt * 64;
#pragma unroll
  for (int it = 0; it < 8; ++it) {
    int fid = it * 256 + t;           // 2048 float4 per tensor
    int r = fid >> 5, c4 = (fid & 31) * 4;
    *(float4*)&Kl[r][c4] = *(const float4*)(k + (size_t)(kvbase + r) * E_DIM + h * DHEAD + c4);
    *(float4*)&Vl[r][c4] = *(const float4*)(v + (size_t)(kvbase + r) * E_DIM + h * DHEAD + c4);
  }
  __syncthreads();
  size_t tb = (size_t)(h * 32 + kvt) * (16 * 64 * 8);
#pragma unroll
  for (int it = 0; it < 4; ++it) {
    int s = it * 256 + t;             // 1024 slots (16 frags x 64 lanes)
    int f = s >> 6, l = s & 63;
    int l15 = l & 15, lh = l >> 4;
    {
      int krow = (f >> 2) * 16 + l15, d0 = (f & 3) * 32 + lh * 8;
      float buf[8];
#pragma unroll
      for (int e = 0; e < 8; ++e) buf[e] = Kl[krow][d0 + e];
      bf16x8 fh, fl; split8(buf, fh, fl);
      *(bf16x8*)(KfH + tb + (size_t)s * 8) = fh;
      *(bf16x8*)(KfL + tb + (size_t)s * 8) = fl;
    }
    {
      int j0 = (f >> 3) * 32 + lh * 8, d = (f & 7) * 16 + l15;
      float buf[8];
#pragma unroll
      for (int e = 0; e < 8; ++e) buf[e] = Vl[j0 + e][d];
      bf16x8 fh, fl; split8(buf, fh, fl);
      *(bf16x8*)(VfH + tb + (size_t)s * 8) = fh;
      *(bf16x8*)(VfL + tb + (size_t)s * 8) = fl;
    }
  }
}

// ---------- kernel 1: gate projections, 4 seq rows per block ----------
__global__ __launch_bounds__(256) void gates_kernel(
    const float* __restrict__ q, const float* __restrict__ k, const float* __restrict__ v,
    const float* __restrict__ igw, const float* __restrict__ igb,
    const float* __restrict__ fgw, const float* __restrict__ fgb,
    float* __restrict__ ig, float* __restrict__ fg) {
  int s0 = blockIdx.x * 4;
  int t = threadIdx.x;
  int c = t & 15, rr = (t >> 4) & 3, ks = t >> 6;
  int row = s0 + rr;
  const float* w = (c < 8 ? igw + c * 3072 : fgw + (c - 8) * 3072);
  float acc = 0.f;
  int k0 = ks * 768;
  for (int kk = k0; kk < k0 + 768; kk += 4) {
    const float* src = (kk < 1024) ? (q + (size_t)row * 1024 + kk)
                     : (kk < 2048) ? (k + (size_t)row * 1024 + (kk - 1024))
                                   : (v + (size_t)row * 1024 + (kk - 2048));
    float4 xv = *(const float4*)src;
    float4 wv = *(const float4*)(w + kk);
    acc = fmaf(xv.x, wv.x, acc);
    acc = fmaf(xv.y, wv.y, acc);
    acc = fmaf(xv.z, wv.z, acc);
    acc = fmaf(xv.w, wv.w, acc);
  }
  __shared__ float red[4][16][4];
  red[rr][c][ks] = acc;
  __syncthreads();
  if (t < 64) {
    int rr2 = t >> 4, c2 = t & 15;
    float s = red[rr2][c2][0] + red[rr2][c2][1] + red[rr2][c2][2] + red[rr2][c2][3];
    int row2 = s0 + rr2;
    if (c2 < 8) ig[c2 * S_LEN + row2] = s + igb[c2];
    else        fg[(c2 - 8) * S_LEN + row2] = s + fgb[c2 - 8];
  }
}

// ---------- kernel 2a: elementwise f64 log-sigmoid ----------
__global__ __launch_bounds__(256) void logsig_kernel(const float* __restrict__ fg,
                                                     double* __restrict__ ls) {
  int i = blockIdx.x * 256 + threadIdx.x;   // 16384 total
  double x = (double)fg[i];
  ls[i] = fmin(x, 0.0) - log1p(exp(-fabs(x)));
}

// ---------- kernel 2b: per-head scan (f64 adds + f32 exp) ----------
__global__ void scan_kernel(const float* __restrict__ ig, const double* __restrict__ ls,
                            double* __restrict__ g, double* __restrict__ Mv,
                            float* __restrict__ rexpv) {
  int h = blockIdx.x;
  int lane = threadIdx.x;  // 64
  double cs0[32];
  const double* lsp = ls + h * S_LEN + lane * 32;
  double run = 0.0;
#pragma unroll
  for (int e = 0; e < 32; ++e) { run += lsp[e]; cs0[e] = run; }
  double incl = run;
#pragma unroll
  for (int off = 1; off < 64; off <<= 1) {
    double nb = __shfl_up(incl, off);
    if (lane >= off) incl += nb;
  }
  double base = __shfl_up(incl, 1);
  if (lane == 0) base = 0.0;
#pragma unroll
  for (int e = 0; e < 32; ++e) cs0[e] += base;

  const float* igp = ig + h * S_LEN + lane * 32;
  double gv[32];
#pragma unroll
  for (int e = 0; e < 32; ++e) {
    gv[e] = (double)igp[e] - cs0[e];
    g[h * S_LEN + lane * 32 + e] = gv[e];
  }
  double pm = -INFINITY;
#pragma unroll
  for (int e = 0; e < 32; ++e) { pm = fmax(pm, gv[e]); gv[e] = pm; }
  double inclm = pm;
#pragma unroll
  for (int off = 1; off < 64; off <<= 1) {
    double nb = __shfl_up(inclm, off);
    if (lane >= off) inclm = fmax(inclm, nb);
  }
  double basem = __shfl_up(inclm, 1);
  if (lane == 0) basem = -INFINITY;
#pragma unroll
  for (int e = 0; e < 32; ++e) {
    double Mi = fmax(basem, gv[e]);
    Mv[h * S_LEN + lane * 32 + e] = Mi;
    rexpv[h * S_LEN + lane * 32 + e] = __expf(-(float)(cs0[e] + Mi));
  }
}

// ---------- kernel 3: barrier-free attention, 16 q-rows/wave, kv-split pairs ----------
__global__ __launch_bounds__(256, 2) void attn_kernel(
    const float* __restrict__ q,
    const __bf16* __restrict__ KfH, const __bf16* __restrict__ KfL,
    const __bf16* __restrict__ VfH, const __bf16* __restrict__ VfL,
    const double* __restrict__ g, const double* __restrict__ Mv,
    const float* __restrict__ rexpv, float* __restrict__ out) {
  // block decode: heaviest group first
  int grp = 31 - (blockIdx.x >> 4);          // 0..31, T = grp+1 kv tiles
  int sub = blockIdx.x & 15;
  int h = sub >> 1;
  int a = sub & 1;
  int tid = threadIdx.x;
  int wave = tid >> 6, lane = tid & 63;
  int lhalf = lane >> 4, l15 = lane & 15;
  int qt   = grp * 4 + a * 2 + (wave >> 1);  // q tile (16 rows)
  int half = wave & 1;
  int T  = grp + 1;
  int Th = (T + 1) >> 1;
  int kb_lo = half ? Th : 0;
  int kb_hi = half ? T  : Th;
  int r0 = qt * 16;
  const float scale = 0.08838834764831845f;  // 1/sqrt(128)

  __shared__ __bf16 PbH[4][16 * 64], PbL[4][16 * 64];
  __shared__ float Comb[2][64][36];

  // Q fragments hi/lo (A operand): lane holds Q[r0+l15][kc*32+lhalf*8+e]
  bf16x8 qfh[4], qfl[4];
  {
    const float* qp = q + (size_t)(r0 + l15) * E_DIM + h * DHEAD + lhalf * 8;
#pragma unroll
    for (int kc = 0; kc < 4; ++kc) {
      float buf[8];
      *(float4*)&buf[0] = *(const float4*)(qp + kc * 32);
      *(float4*)&buf[4] = *(const float4*)(qp + kc * 32 + 4);
      split8(buf, qfh[kc], qfl[kc]);
    }
  }
  double Mreg[4];
  float rexp[4];
#pragma unroll
  for (int rg = 0; rg < 4; ++rg) {
    int i = r0 + lhalf * 4 + rg;
    Mreg[rg] = Mv[h * S_LEN + i];
    rexp[rg] = rexpv[h * S_LEN + i];
  }

  f32x4 acc[8];
#pragma unroll
  for (int nt = 0; nt < 8; ++nt) acc[nt] = (f32x4){0.f, 0.f, 0.f, 0.f};
  float bacc[4] = {0.f, 0.f, 0.f, 0.f};

  char* PwH = (char*)&PbH[wave][0];
  char* PwL = (char*)&PbL[wave][0];

  for (int kb = kb_lo; kb < kb_hi; ++kb) {
    int kvbase = kb * 64;
    const __bf16* kbH = KfH + (size_t)((h * 32 + kb) * 16) * 512 + lane * 8;
    const __bf16* kbL = KfL + (size_t)((h * 32 + kb) * 16) * 512 + lane * 8;
    const __bf16* vbH = VfH + (size_t)((h * 32 + kb) * 16) * 512 + lane * 8;
    const __bf16* vbL = VfL + (size_t)((h * 32 + kb) * 16) * 512 + lane * 8;

    // ---- QK^T: 4 col-tiles of 16, split product ----
#pragma unroll
    for (int ct = 0; ct < 4; ++ct) {
      f32x4 cacc = (f32x4){0.f, 0.f, 0.f, 0.f};
#pragma unroll
      for (int kc = 0; kc < 4; ++kc) {
        int f = ct * 4 + kc;
        bf16x8 kh = *(const bf16x8*)(kbH + (size_t)f * 512);
        bf16x8 kl = *(const bf16x8*)(kbL + (size_t)f * 512);
        cacc = __builtin_amdgcn_mfma_f32_16x16x32_bf16(qfh[kc], kh, cacc, 0, 0, 0);
        cacc = __builtin_amdgcn_mfma_f32_16x16x32_bf16(qfh[kc], kl, cacc, 0, 0, 0);
        cacc = __builtin_amdgcn_mfma_f32_16x16x32_bf16(qfl[kc], kh, cacc, 0, 0, 0);
      }
      int j = kvbase + ct * 16 + l15;
      double gj = g[h * S_LEN + j];
#pragma unroll
      for (int rg = 0; rg < 4; ++rg) {
        int i = r0 + lhalf * 4 + rg;
        float pv = 0.f;
        if (j <= i) pv = cacc[rg] * scale * __expf((float)(gj - Mreg[rg]));
        bacc[rg] += pv;
        __bf16 ph = (__bf16)pv;
        __bf16 pl = (__bf16)(pv - (float)ph);
        int prow = lhalf * 4 + rg;
        int pcol = ct * 16 + l15;
        int poff = (prow * 128 + pcol * 2) ^ ((prow & 7) << 4);
        *(__bf16*)(PwH + poff) = ph;
        *(__bf16*)(PwL + poff) = pl;
      }
    }
    // ---- PV: P[16x64] @ V[64x128], split product (per-wave P, no barrier) ----
#pragma unroll
    for (int kc2 = 0; kc2 < 2; ++kc2) {
      int poff = (l15 * 128 + (kc2 * 32 + lhalf * 8) * 2) ^ ((l15 & 7) << 4);
      bf16x8 pfh = *(const bf16x8*)(PwH + poff);
      bf16x8 pfl = *(const bf16x8*)(PwL + poff);
#pragma unroll
      for (int nt = 0; nt < 8; ++nt) {
        int f = kc2 * 8 + nt;
        bf16x8 vfh = *(const bf16x8*)(vbH + (size_t)f * 512);
        bf16x8 vfl = *(const bf16x8*)(vbL + (size_t)f * 512);
        acc[nt] = __builtin_amdgcn_mfma_f32_16x16x32_bf16(pfh, vfh, acc[nt], 0, 0, 0);
        acc[nt] = __builtin_amdgcn_mfma_f32_16x16x32_bf16(pfh, vfl, acc[nt], 0, 0, 0);
        acc[nt] = __builtin_amdgcn_mfma_f32_16x16x32_bf16(pfl, vfh, acc[nt], 0, 0, 0);
      }
    }
  }

  // ---- combine the two kv-halves of each q-tile ----
  int qtl = wave >> 1;
  if (half == 1) {
#pragma unroll
    for (int nt = 0; nt < 8; ++nt)
#pragma unroll
      for (int rg = 0; rg < 4; ++rg) Comb[qtl][lane][nt * 4 + rg] = acc[nt][rg];
#pragma unroll
    for (int rg = 0; rg < 4; ++rg) Comb[qtl][lane][32 + rg] = bacc[rg];
  }
  __syncthreads();
  if (half == 0) {
#pragma unroll
    for (int nt = 0; nt < 8; ++nt)
#pragma unroll
      for (int rg = 0; rg < 4; ++rg) acc[nt][rg] += Comb[qtl][lane][nt * 4 + rg];
#pragma unroll
    for (int rg = 0; rg < 4; ++rg) bacc[rg] += Comb[qtl][lane][32 + rg];

    float invn[4];
#pragma unroll
    for (int rg = 0; rg < 4; ++rg) {
      float b = bacc[rg];
      b += __shfl_xor(b, 1); b += __shfl_xor(b, 2);
      b += __shfl_xor(b, 4); b += __shfl_xor(b, 8);
      float norm = fmaxf(fabsf(b), rexp[rg]) + MEPS;
      invn[rg] = 1.f / norm;
    }
#pragma unroll
    for (int nt = 0; nt < 8; ++nt)
#pragma unroll
      for (int rg = 0; rg < 4; ++rg) {
        int i = r0 + lhalf * 4 + rg;
        out[(size_t)i * E_DIM + h * DHEAD + nt * 16 + l15] = acc[nt][rg] * invn[rg];
      }
  }
}

// ---------- kernel 4: in-place LayerNorm over E ----------
__global__ __launch_bounds__(256) void ln_kernel(float* __restrict__ io, const float* __restrict__ lnw) {
  int s = blockIdx.x, t = threadIdx.x;
  float4 x = *(const float4*)(io + (size_t)s * E_DIM + t * 4);
  float sum = x.x + x.y + x.z + x.w;
  float sq  = x.x * x.x + x.y * x.y + x.z * x.z + x.w * x.w;
#pragma unroll
  for (int off = 1; off < 64; off <<= 1) {
    sum += __shfl_xor(sum, off);
    sq  += __shfl_xor(sq, off);
  }
  __shared__ float ps[4][2];
  int wave = t >> 6;
  if ((t & 63) == 0) { ps[wave][0] = sum; ps[wave][1] = sq; }
  __syncthreads();
  float ts = ps[0][0] + ps[1][0] + ps[2][0] + ps[3][0];
  float tq = ps[0][1] + ps[1][1] + ps[2][1] + ps[3][1];
  float mu = ts * (1.f / E_DIM);
  float var = tq * (1.f / E_DIM) - mu * mu;
  float inv = rsqrtf(var + LNEPS);
  float4 w = *(const float4*)(lnw + t * 4);
  float4 o;
  o.x = (x.x - mu) * inv * w.x;
  o.y = (x.y - mu) * inv * w.y;
  o.z = (x.z - mu) * inv * w.z;
  o.w = (x.w - mu) * inv * w.w;
  *(float4*)(io + (size_t)s * E_DIM + t * 4) = o;
}

extern "C" void kernel_launch(void* const* d_in, const int* in_sizes, int n_in,
                              void* d_out, int out_size, void* d_ws, size_t ws_size,
                              hipStream_t stream) {
  const float* q   = (const float*)d_in[0];
  const float* k   = (const float*)d_in[1];
  const float* v   = (const float*)d_in[2];
  const float* igw = (const float*)d_in[3];
  const float* igb = (const float*)d_in[4];
  const float* fgw = (const float*)d_in[5];
  const float* fgb = (const float*)d_in[6];
  const float* lnw = (const float*)d_in[7];
  float* out = (float*)d_out;

  char* base = (char*)d_ws;
  float*  ig    = (float*)(base + 0);
  float*  fg    = (float*)(base + 64 * 1024);
  float*  rexpv = (float*)(base + 128 * 1024);
  double* ls    = (double*)(base + 256 * 1024);
  double* g64   = (double*)(base + 384 * 1024);
  double* M64   = (double*)(base + 512 * 1024);
  __bf16* KfH   = (__bf16*)(base + 1 * 1024 * 1024);
  __bf16* KfL   = KfH + (size_t)NHEAD * 32 * 16 * 64 * 8;   // +4MB
  __bf16* VfH   = KfL + (size_t)NHEAD * 32 * 16 * 64 * 8;
  __bf16* VfL   = VfH + (size_t)NHEAD * 32 * 16 * 64 * 8;

  convert_kernel<<<dim3(256), dim3(256), 0, stream>>>(k, v, KfH, KfL, VfH, VfL);
  gates_kernel<<<dim3(512), dim3(256), 0, stream>>>(q, k, v, igw, igb, fgw, fgb, ig, fg);
  logsig_kernel<<<dim3(64), dim3(256), 0, stream>>>(fg, ls);
  scan_kernel<<<dim3(NHEAD), dim3(64), 0, stream>>>(ig, ls, g64, M64, rexpv);
  attn_kernel<<<dim3(512), dim3(256), 0, stream>>>(q, KfH, KfL, VfH, VfL, g64, M64, rexpv, out);
  ln_kernel<<<dim3(S_LEN), dim3(256), 0, stream>>>(out, lnw);
}

// Round 4
// 96.604 us; speedup vs baseline: 2.1346x; 2.1346x over previous
//
#include <hip/hip_runtime.h>
#include <hip/hip_bf16.h>
#include <math.h>

#define S_LEN 2048
#define E_DIM 1024
#define NHEAD 8
#define DHEAD 128
#define MEPS 1e-6f
#define LNEPS 1e-5f

typedef __bf16 bf16x8 __attribute__((ext_vector_type(8)));
typedef float f32x4 __attribute__((ext_vector_type(4)));

__device__ inline void split8(const float* x, bf16x8& hi, bf16x8& lo) {
#pragma unroll
  for (int e = 0; e < 8; ++e) {
    float v = x[e];
    __bf16 h = (__bf16)v;
    hi[e] = h;
    lo[e] = (__bf16)(v - (float)h);
  }
}

// ---------- kernel 1: gates. wave-per-output-column, register-cached weights ----------
// grid 256 x 1024 threads (16 waves). wave w -> column c=w (c<8: igate head c, else fgate head c-8)
__global__ __launch_bounds__(1024) void gates_kernel(
    const float* __restrict__ q, const float* __restrict__ k, const float* __restrict__ v,
    const float* __restrict__ igw, const float* __restrict__ igb,
    const float* __restrict__ fgw, const float* __restrict__ fgb,
    float* __restrict__ ig, double* __restrict__ ls) {
  int t = threadIdx.x, wave = t >> 6, lane = t & 63;
  int c = wave;  // 0..15
  const float* wrow = (c < 8) ? (igw + c * 3072) : (fgw + (c - 8) * 3072);
  float4 wreg[12];
#pragma unroll
  for (int j = 0; j < 12; ++j) wreg[j] = *(const float4*)(wrow + j * 256 + lane * 4);
  int r0 = blockIdx.x * 8;
  for (int r = 0; r < 8; ++r) {
    int row = r0 + r;
    float acc = 0.f;
#pragma unroll
    for (int j = 0; j < 12; ++j) {
      const float* xs = (j < 4) ? (q + (size_t)row * 1024 + j * 256)
                      : (j < 8) ? (k + (size_t)row * 1024 + (j - 4) * 256)
                                : (v + (size_t)row * 1024 + (j - 8) * 256);
      float4 xv = *(const float4*)(xs + lane * 4);
      acc = fmaf(xv.x, wreg[j].x, acc);
      acc = fmaf(xv.y, wreg[j].y, acc);
      acc = fmaf(xv.z, wreg[j].z, acc);
      acc = fmaf(xv.w, wreg[j].w, acc);
    }
#pragma unroll
    for (int off = 1; off < 64; off <<= 1) acc += __shfl_xor(acc, off);
    if (lane == 0) {
      if (c < 8) {
        ig[c * S_LEN + row] = acc + igb[c];
      } else {
        double x = (double)(acc + fgb[c - 8]);
        ls[(c - 8) * S_LEN + row] = fmin(x, 0.0) - log1p(exp(-fabs(x)));
      }
    }
  }
}

// ---------- kernel 2: per-head f64 scan ----------
__global__ void scan_kernel(const float* __restrict__ ig, const double* __restrict__ ls,
                            double* __restrict__ g, double* __restrict__ Mv,
                            float* __restrict__ rexpv) {
  int h = blockIdx.x;
  int lane = threadIdx.x;  // 64
  double cs0[32];
  const double* lsp = ls + h * S_LEN + lane * 32;
  double run = 0.0;
#pragma unroll
  for (int e = 0; e < 32; ++e) { run += lsp[e]; cs0[e] = run; }
  double incl = run;
#pragma unroll
  for (int off = 1; off < 64; off <<= 1) {
    double nb = __shfl_up(incl, off);
    if (lane >= off) incl += nb;
  }
  double base = __shfl_up(incl, 1);
  if (lane == 0) base = 0.0;
#pragma unroll
  for (int e = 0; e < 32; ++e) cs0[e] += base;

  const float* igp = ig + h * S_LEN + lane * 32;
  double gv[32];
#pragma unroll
  for (int e = 0; e < 32; ++e) {
    gv[e] = (double)igp[e] - cs0[e];
    g[h * S_LEN + lane * 32 + e] = gv[e];
  }
  double pm = -INFINITY;
#pragma unroll
  for (int e = 0; e < 32; ++e) { pm = fmax(pm, gv[e]); gv[e] = pm; }
  double inclm = pm;
#pragma unroll
  for (int off = 1; off < 64; off <<= 1) {
    double nb = __shfl_up(inclm, off);
    if (lane >= off) inclm = fmax(inclm, nb);
  }
  double basem = __shfl_up(inclm, 1);
  if (lane == 0) basem = -INFINITY;
#pragma unroll
  for (int e = 0; e < 32; ++e) {
    double Mi = fmax(basem, gv[e]);
    Mv[h * S_LEN + lane * 32 + e] = Mi;
    rexpv[h * S_LEN + lane * 32 + e] = __expf(-(float)(cs0[e] + Mi));
  }
}

// ---------- kernel 3: pre-convert K,V to fragment-major bf16 (K hi+lo, V hi) ----------
// KfH/KfL: [h][kvt][f=ct*4+kc][lane][8]  elem = K[kvt*64+ct*16+(l&15)][h*128+kc*32+(l>>4)*8+e]
// VfH:     [h][kvt][f=kc2*8+nt][lane][8] elem = V[kvt*64+kc2*32+(l>>4)*8+e][h*128+nt*16+(l&15)]
__global__ __launch_bounds__(256) void convert_kernel(
    const float* __restrict__ k, const float* __restrict__ v,
    __bf16* __restrict__ KfH, __bf16* __restrict__ KfL, __bf16* __restrict__ VfH) {
  int h = blockIdx.x >> 5, kvt = blockIdx.x & 31;
  int t = threadIdx.x;
  __shared__ float Kl[64][132], Vl[64][132];
  int kvbase = kvt * 64;
#pragma unroll
  for (int it = 0; it < 8; ++it) {
    int fid = it * 256 + t;
    int r = fid >> 5, c4 = (fid & 31) * 4;
    *(float4*)&Kl[r][c4] = *(const float4*)(k + (size_t)(kvbase + r) * E_DIM + h * DHEAD + c4);
    *(float4*)&Vl[r][c4] = *(const float4*)(v + (size_t)(kvbase + r) * E_DIM + h * DHEAD + c4);
  }
  __syncthreads();
  size_t tb = (size_t)(h * 32 + kvt) * 8192;
#pragma unroll
  for (int it = 0; it < 4; ++it) {
    int s = it * 256 + t;
    int f = s >> 6, l = s & 63;
    int l15 = l & 15, lh = l >> 4;
    {
      int krow = (f >> 2) * 16 + l15, d0 = (f & 3) * 32 + lh * 8;
      float buf[8];
#pragma unroll
      for (int e = 0; e < 8; ++e) buf[e] = Kl[krow][d0 + e];
      bf16x8 fh, fl; split8(buf, fh, fl);
      *(bf16x8*)(KfH + tb + (size_t)s * 8) = fh;
      *(bf16x8*)(KfL + tb + (size_t)s * 8) = fl;
    }
    {
      int j0 = (f >> 3) * 32 + lh * 8, d = (f & 7) * 16 + l15;
      bf16x8 fh;
#pragma unroll
      for (int e = 0; e < 8; ++e) fh[e] = (__bf16)Vl[j0 + e][d];
      *(bf16x8*)(VfH + tb + (size_t)s * 8) = fh;
    }
  }
}

// ---------- kernel 4: attention. block = (h, qgroup128, kv-half), 8 waves, T14 pipeline ----------
__global__ __launch_bounds__(512, 2) void attn_kernel(
    const float* __restrict__ q,
    const __bf16* __restrict__ KfH, const __bf16* __restrict__ KfL,
    const __bf16* __restrict__ VfH,
    const double* __restrict__ g, const double* __restrict__ Mv,
    const float* __restrict__ rexpv,
    float* __restrict__ part, float* __restrict__ bpart) {
  int idx = blockIdx.x;
  int h = idx & 7;                 // XCD-pinned per head
  int j2 = idx >> 3;               // 0..31
  int qg = 15 - (j2 >> 1);         // heavy-first
  int half = j2 & 1;
  int Th = qg + 1;                 // tiles per half (equal halves, T=2qg+2)
  int kb_lo = half ? Th : 0;
  int kb_hi = half ? 2 * qg + 2 : Th;
  int tid = threadIdx.x, wave = tid >> 6, lane = tid & 63;
  int lhalf = lane >> 4, l15 = lane & 15;
  int wr0 = qg * 128 + wave * 16;
  const float scale = 0.08838834764831845f;  // 1/sqrt(128)

  __shared__ float4 smem4[80 * 1024 / 16];   // [KH 16K][KL 16K][VH 16K][P 8x4K]
  char* smem = (char*)smem4;
  char* PwH = smem + 48 * 1024 + wave * 4096;
  char* PwL = PwH + 2048;

  // Q fragments hi/lo
  bf16x8 qfh[4], qfl[4];
  {
    const float* qp = q + (size_t)(wr0 + l15) * E_DIM + h * DHEAD + lhalf * 8;
#pragma unroll
    for (int kc = 0; kc < 4; ++kc) {
      float buf[8];
      *(float4*)&buf[0] = *(const float4*)(qp + kc * 32);
      *(float4*)&buf[4] = *(const float4*)(qp + kc * 32 + 4);
      split8(buf, qfh[kc], qfl[kc]);
    }
  }
  double Mreg[4];
  float rexp_[4];
#pragma unroll
  for (int rg = 0; rg < 4; ++rg) {
    int i = wr0 + lhalf * 4 + rg;
    Mreg[rg] = Mv[h * S_LEN + i];
    rexp_[rg] = rexpv[h * S_LEN + i];
  }

  f32x4 acc[8];
#pragma unroll
  for (int nt = 0; nt < 8; ++nt) acc[nt] = (f32x4){0.f, 0.f, 0.f, 0.f};
  float bacc[4] = {0.f, 0.f, 0.f, 0.f};

  bf16x8 sreg[6];
  auto STAGE = [&](int kb) {
    size_t tb = (size_t)(h * 32 + kb) * 8192;
#pragma unroll
    for (int jj = 0; jj < 2; ++jj) {
      sreg[jj]     = *(const bf16x8*)(KfH + tb + (size_t)(jj * 512 + tid) * 8);
      sreg[2 + jj] = *(const bf16x8*)(KfL + tb + (size_t)(jj * 512 + tid) * 8);
      sreg[4 + jj] = *(const bf16x8*)(VfH + tb + (size_t)(jj * 512 + tid) * 8);
    }
  };
  STAGE(kb_lo);

  for (int kb = kb_lo; kb < kb_hi; ++kb) {
    int kvbase = kb * 64;
    // regs -> LDS (waits on staged loads automatically)
#pragma unroll
    for (int jj = 0; jj < 2; ++jj) {
      *(bf16x8*)(smem +          (jj * 512 + tid) * 16) = sreg[jj];
      *(bf16x8*)(smem + 16384 +  (jj * 512 + tid) * 16) = sreg[2 + jj];
      *(bf16x8*)(smem + 32768 +  (jj * 512 + tid) * 16) = sreg[4 + jj];
    }
    if (kb + 1 < kb_hi) STAGE(kb + 1);   // next tile flies during compute
    asm volatile("s_waitcnt lgkmcnt(0)" ::: "memory");
    __builtin_amdgcn_s_barrier();

    // prefetch per-lane g values
    double gj4[4];
#pragma unroll
    for (int ct = 0; ct < 4; ++ct) gj4[ct] = g[h * S_LEN + kvbase + ct * 16 + l15];

    // ---- QK^T: 4 independent accumulator chains ----
    f32x4 cacc[4];
#pragma unroll
    for (int ct = 0; ct < 4; ++ct) cacc[ct] = (f32x4){0.f, 0.f, 0.f, 0.f};
    __builtin_amdgcn_s_setprio(1);
#pragma unroll
    for (int kc = 0; kc < 4; ++kc) {
#pragma unroll
      for (int ct = 0; ct < 4; ++ct) {
        int f = ct * 4 + kc;
        bf16x8 kh = *(const bf16x8*)(smem + f * 1024 + lane * 16);
        bf16x8 kl = *(const bf16x8*)(smem + 16384 + f * 1024 + lane * 16);
        cacc[ct] = __builtin_amdgcn_mfma_f32_16x16x32_bf16(qfh[kc], kh, cacc[ct], 0, 0, 0);
        cacc[ct] = __builtin_amdgcn_mfma_f32_16x16x32_bf16(qfh[kc], kl, cacc[ct], 0, 0, 0);
        cacc[ct] = __builtin_amdgcn_mfma_f32_16x16x32_bf16(qfl[kc], kh, cacc[ct], 0, 0, 0);
      }
    }
    __builtin_amdgcn_s_setprio(0);

    // ---- weights + P store (per-wave LDS, swizzled) ----
#pragma unroll
    for (int ct = 0; ct < 4; ++ct) {
      int j = kvbase + ct * 16 + l15;
#pragma unroll
      for (int rg = 0; rg < 4; ++rg) {
        int i = wr0 + lhalf * 4 + rg;
        float pv = 0.f;
        if (j <= i) pv = cacc[ct][rg] * scale * __expf((float)(gj4[ct] - Mreg[rg]));
        bacc[rg] += pv;
        __bf16 ph = (__bf16)pv;
        __bf16 pl = (__bf16)(pv - (float)ph);
        int poff = ((lhalf * 4 + rg) * 128 + (ct * 16 + l15) * 2) ^ (((lhalf * 4 + rg) & 7) << 4);
        *(__bf16*)(PwH + poff) = ph;
        *(__bf16*)(PwL + poff) = pl;
      }
    }

    // ---- PV: 8 independent chains ----
    __builtin_amdgcn_s_setprio(1);
#pragma unroll
    for (int kc2 = 0; kc2 < 2; ++kc2) {
      int poff = (l15 * 128 + (kc2 * 32 + lhalf * 8) * 2) ^ ((l15 & 7) << 4);
      bf16x8 pfh = *(const bf16x8*)(PwH + poff);
      bf16x8 pfl = *(const bf16x8*)(PwL + poff);
#pragma unroll
      for (int nt = 0; nt < 8; ++nt) {
        int f2 = kc2 * 8 + nt;
        bf16x8 vfh = *(const bf16x8*)(smem + 32768 + f2 * 1024 + lane * 16);
        acc[nt] = __builtin_amdgcn_mfma_f32_16x16x32_bf16(pfh, vfh, acc[nt], 0, 0, 0);
        acc[nt] = __builtin_amdgcn_mfma_f32_16x16x32_bf16(pfl, vfh, acc[nt], 0, 0, 0);
      }
    }
    __builtin_amdgcn_s_setprio(0);
    __builtin_amdgcn_s_barrier();   // all waves done reading before restage
  }

  // ---- partial write ----
  float bred[4];
#pragma unroll
  for (int rg = 0; rg < 4; ++rg) {
    float b = bacc[rg];
    b += __shfl_xor(b, 1); b += __shfl_xor(b, 2);
    b += __shfl_xor(b, 4); b += __shfl_xor(b, 8);
    bred[rg] = b;
  }
  int task = (h * 16 + qg) * 2 + half;
  if (l15 == 0) {
#pragma unroll
    for (int rg = 0; rg < 4; ++rg)
      bpart[task * 128 + wave * 16 + lhalf * 4 + rg] = bred[rg];
  }
  size_t pb = ((size_t)task * 128 + wave * 16) * 128;
#pragma unroll
  for (int nt = 0; nt < 8; ++nt)
#pragma unroll
    for (int rg = 0; rg < 4; ++rg)
      part[pb + (size_t)(lhalf * 4 + rg) * 128 + nt * 16 + l15] = acc[nt][rg];
}

// ---------- kernel 5: combine halves + normalize + LayerNorm (fused) ----------
__global__ __launch_bounds__(256) void combine_ln_kernel(
    const float* __restrict__ part, const float* __restrict__ bpart,
    const float* __restrict__ rexpv, const float* __restrict__ lnw,
    float* __restrict__ out) {
  int t = blockIdx.x;          // token
  int tid = threadIdx.x;
  int qg = t >> 7, rloc = t & 127;
  int e = tid * 4;
  int h = e >> 7, d = e & 127;
  int task0 = (h * 16 + qg) * 2;
  size_t p0 = ((size_t)task0 * 128 + rloc) * 128 + d;
  size_t p1 = ((size_t)(task0 + 1) * 128 + rloc) * 128 + d;
  float4 a = *(const float4*)(part + p0);
  float4 b4 = *(const float4*)(part + p1);
  float b = bpart[task0 * 128 + rloc] + bpart[(task0 + 1) * 128 + rloc];
  float norm = fmaxf(fabsf(b), rexpv[h * S_LEN + t]) + MEPS;
  float inv = 1.f / norm;
  float4 hv;
  hv.x = (a.x + b4.x) * inv; hv.y = (a.y + b4.y) * inv;
  hv.z = (a.z + b4.z) * inv; hv.w = (a.w + b4.w) * inv;

  float sum = hv.x + hv.y + hv.z + hv.w;
  float sq  = hv.x * hv.x + hv.y * hv.y + hv.z * hv.z + hv.w * hv.w;
#pragma unroll
  for (int off = 1; off < 64; off <<= 1) {
    sum += __shfl_xor(sum, off);
    sq  += __shfl_xor(sq, off);
  }
  __shared__ float ps[4][2];
  int wave = tid >> 6;
  if ((tid & 63) == 0) { ps[wave][0] = sum; ps[wave][1] = sq; }
  __syncthreads();
  float ts = ps[0][0] + ps[1][0] + ps[2][0] + ps[3][0];
  float tq = ps[0][1] + ps[1][1] + ps[2][1] + ps[3][1];
  float mu = ts * (1.f / E_DIM);
  float var = tq * (1.f / E_DIM) - mu * mu;
  float rstd = rsqrtf(var + LNEPS);
  float4 w = *(const float4*)(lnw + e);
  float4 o;
  o.x = (hv.x - mu) * rstd * w.x;
  o.y = (hv.y - mu) * rstd * w.y;
  o.z = (hv.z - mu) * rstd * w.z;
  o.w = (hv.w - mu) * rstd * w.w;
  *(float4*)(out + (size_t)t * E_DIM + e) = o;
}

extern "C" void kernel_launch(void* const* d_in, const int* in_sizes, int n_in,
                              void* d_out, int out_size, void* d_ws, size_t ws_size,
                              hipStream_t stream) {
  const float* q   = (const float*)d_in[0];
  const float* k   = (const float*)d_in[1];
  const float* v   = (const float*)d_in[2];
  const float* igw = (const float*)d_in[3];
  const float* igb = (const float*)d_in[4];
  const float* fgw = (const float*)d_in[5];
  const float* fgb = (const float*)d_in[6];
  const float* lnw = (const float*)d_in[7];
  float* out = (float*)d_out;

  char* base = (char*)d_ws;
  float*  ig    = (float*)(base + 0);            // 64KB
  float*  rexpv = (float*)(base + 64 * 1024);    // 64KB
  double* ls    = (double*)(base + 128 * 1024);  // 128KB
  double* g64   = (double*)(base + 256 * 1024);  // 128KB
  double* M64   = (double*)(base + 384 * 1024);  // 128KB
  __bf16* KfH   = (__bf16*)(base + 1 * 1024 * 1024);   // 4MB
  __bf16* KfL   = (__bf16*)(base + 5 * 1024 * 1024);   // 4MB
  __bf16* VfH   = (__bf16*)(base + 9 * 1024 * 1024);   // 4MB
  float*  part  = (float*)(base + 13 * 1024 * 1024);   // 16MB
  float*  bpart = (float*)(base + 30 * 1024 * 1024);   // 128KB

  gates_kernel<<<dim3(256), dim3(1024), 0, stream>>>(q, k, v, igw, igb, fgw, fgb, ig, ls);
  scan_kernel<<<dim3(NHEAD), dim3(64), 0, stream>>>(ig, ls, g64, M64, rexpv);
  convert_kernel<<<dim3(256), dim3(256), 0, stream>>>(k, v, KfH, KfL, VfH);
  attn_kernel<<<dim3(256), dim3(512), 0, stream>>>(q, KfH, KfL, VfH, g64, M64, rexpv, part, bpart);
  combine_ln_kernel<<<dim3(S_LEN), dim3(256), 0, stream>>>(part, bpart, rexpv, lnw, out);
}